// Round 1
// baseline (634.456 us; speedup 1.0000x reference)
//
#include <hip/hip_runtime.h>
#include <cstdint>
#include <cstddef>

// Problem: Top-1 MoE gate. s=8192 tokens, e=64 experts, d=2048, capacity=128.
// Outputs concatenated in d_out (float32): [l_aux(1), combine(8192*64*128), mask(8192*64*128)]

#define S_TOK 8192
#define NEXP 64
#define DIM 2048
#define CAP 128
#define TOK_PER_BLK 32
#define KC 32
#define COMB_ELEMS ((size_t)S_TOK * NEXP * CAP)   // 67108864

// ---------------------------------------------------------------------------
// Kernel 1: fused logits GEMM (fp32) + softmax + argmax + per-expert gate sums
// grid 256 blocks x 256 threads; each block: 32 tokens x 64 experts.
// thread (ty=tid>>5, tx=tid&31): 4 tokens (t0=4*ty) x 2 experts (e0=2*tx).
// ---------------------------------------------------------------------------
__global__ __launch_bounds__(256) void gate_kernel(
    const float* __restrict__ x, const float* __restrict__ wg,
    int* __restrict__ idx_out, float* __restrict__ gate_out,
    float* __restrict__ gsum)
{
    __shared__ float xs[KC][TOK_PER_BLK];   // k-major x tile, 4 KB
    __shared__ float wsh[KC][NEXP];         // k-major wg tile, 8 KB
    __shared__ float sme[NEXP];

    const int tid = threadIdx.x;
    const int tok0 = blockIdx.x * TOK_PER_BLK;
    const int ty = tid >> 5;          // 0..7
    const int tx = tid & 31;          // 0..31
    const int t0 = ty * 4;
    const int e0 = tx * 2;

    if (tid < NEXP) sme[tid] = 0.0f;

    float acc[4][2];
#pragma unroll
    for (int i = 0; i < 4; ++i) { acc[i][0] = 0.0f; acc[i][1] = 0.0f; }

    // staging assignment: x tile -> thread loads one float4 (token xt, k4=xk)
    const int xt = tid >> 3;               // 0..31
    const int xk = (tid & 7) * 4;          // 0,4,..,28
    const float* xrow = x + (size_t)(tok0 + xt) * DIM + xk;
    // wg tile -> thread loads two float4 (experts we0, we0+32)
    const int we0 = tid >> 3;              // 0..31
    const float* wrow0 = wg + (size_t)we0 * DIM + xk;
    const float* wrow1 = wrow0 + (size_t)32 * DIM;

    // software pipeline: prefetch chunk 0
    float4 xv  = *(const float4*)(xrow);
    float4 wv0 = *(const float4*)(wrow0);
    float4 wv1 = *(const float4*)(wrow1);

    for (int kc = 0; kc < DIM; kc += KC) {
        __syncthreads();
        // write staged regs into LDS (transposed to k-major)
        xs[xk + 0][xt] = xv.x; xs[xk + 1][xt] = xv.y;
        xs[xk + 2][xt] = xv.z; xs[xk + 3][xt] = xv.w;
        wsh[xk + 0][we0] = wv0.x; wsh[xk + 1][we0] = wv0.y;
        wsh[xk + 2][we0] = wv0.z; wsh[xk + 3][we0] = wv0.w;
        wsh[xk + 0][we0 + 32] = wv1.x; wsh[xk + 1][we0 + 32] = wv1.y;
        wsh[xk + 2][we0 + 32] = wv1.z; wsh[xk + 3][we0 + 32] = wv1.w;
        __syncthreads();
        // prefetch next chunk while computing this one
        if (kc + KC < DIM) {
            xv  = *(const float4*)(xrow + kc + KC);
            wv0 = *(const float4*)(wrow0 + kc + KC);
            wv1 = *(const float4*)(wrow1 + kc + KC);
        }
#pragma unroll
        for (int k = 0; k < KC; ++k) {
            float4 xa = *(const float4*)&xs[k][t0];
            float2 wb = *(const float2*)&wsh[k][e0];
            acc[0][0] += xa.x * wb.x; acc[0][1] += xa.x * wb.y;
            acc[1][0] += xa.y * wb.x; acc[1][1] += xa.y * wb.y;
            acc[2][0] += xa.z * wb.x; acc[2][1] += xa.z * wb.y;
            acc[3][0] += xa.w * wb.x; acc[3][1] += xa.w * wb.y;
        }
    }

    // per-token softmax + argmax across 32 lanes (same ty group)
    float gm0 = 0.0f, gm1 = 0.0f;
#pragma unroll
    for (int i = 0; i < 4; ++i) {
        float l0 = acc[i][0], l1 = acc[i][1];
        float v; int ix;
        if (l1 > l0) { v = l1; ix = e0 + 1; } else { v = l0; ix = e0; }
#pragma unroll
        for (int off = 16; off; off >>= 1) {
            float ov = __shfl_xor(v, off, 32);
            int   oi = __shfl_xor(ix, off, 32);
            if (ov > v || (ov == v && oi < ix)) { v = ov; ix = oi; }
        }
        // v = row max (all 32 lanes agree), ix = first-index argmax
        float z0 = __expf(l0 - v), z1 = __expf(l1 - v);
        float zs = z0 + z1;
#pragma unroll
        for (int off = 16; off; off >>= 1) zs += __shfl_xor(zs, off, 32);
        float inv = 1.0f / zs;              // gate value at argmax
        gm0 += z0 * inv; gm1 += z1 * inv;   // per-expert gate contributions (me)
        if (tx == 0) {
            int tok = tok0 + t0 + i;
            idx_out[tok]  = ix;
            gate_out[tok] = inv;
        }
    }
    atomicAdd(&sme[e0], gm0);
    atomicAdd(&sme[e0 + 1], gm1);
    __syncthreads();
    if (tid < NEXP) atomicAdd(&gsum[tid], sme[tid]);
}

// ---------------------------------------------------------------------------
// Kernel 2: ordered per-expert rank (cumsum of one-hot) + capacity filter +
// sparse scatter into combine/mask + l_aux. Single block, 1024 threads.
// Wave-level match-any via 6 ballots (experts are 6-bit).
// ---------------------------------------------------------------------------
__global__ __launch_bounds__(1024) void scan_scatter(
    const int* __restrict__ idx, const float* __restrict__ gate,
    const float* __restrict__ gsum, float* __restrict__ out)
{
    __shared__ int wavecnt[16][NEXP];
    __shared__ int basecnt[NEXP];
    const int tid  = threadIdx.x;
    const int lane = tid & 63;
    const int wv   = tid >> 6;

    if (tid < NEXP) basecnt[tid] = 0;
    __syncthreads();

    for (int it = 0; it < S_TOK / 1024; ++it) {
        int tok = it * 1024 + tid;
        int e = idx[tok];
        unsigned long long m = ~0ull, lm = ~0ull;
#pragma unroll
        for (int b = 0; b < 6; ++b) {
            unsigned long long bal = __ballot((e >> b) & 1);
            m  &= ((e >> b) & 1)    ? bal : ~bal;   // lanes with my expert
            lm &= ((lane >> b) & 1) ? bal : ~bal;   // lanes with expert == lane id
        }
        int rank = __popcll(m & ((1ull << lane) - 1ull));  // my order within wave
        wavecnt[wv][lane] = __popcll(lm);                  // wave histogram
        __syncthreads();
        int off = 0;
        for (int w = 0; w < wv; ++w) off += wavecnt[w][e];
        int loc = basecnt[e] + off + rank;
        if (loc < CAP) {
            size_t base = 1 + (size_t)tok * (NEXP * CAP) + (size_t)e * CAP + loc;
            out[base] = gate[tok];            // combine_weights
            out[base + COMB_ELEMS] = 1.0f;    // dispatch_mask (bool -> 1.0)
        }
        __syncthreads();
        if (tid < NEXP) {
            int tot = 0;
#pragma unroll
            for (int w = 0; w < 16; ++w) tot += wavecnt[w][tid];
            basecnt[tid] += tot;
        }
        __syncthreads();
    }

    // l_aux = e/s^2 * sum_e gsum[e]*count[e] ; e/s^2 = 64/8192^2
    if (tid < NEXP) {
        float p = gsum[tid] * (float)basecnt[tid];
#pragma unroll
        for (int off = 32; off; off >>= 1) p += __shfl_xor(p, off, 64);
        if (tid == 0) out[0] = p * 9.5367431640625e-07f;
    }
}

extern "C" void kernel_launch(void* const* d_in, const int* in_sizes, int n_in,
                              void* d_out, int out_size, void* d_ws, size_t ws_size,
                              hipStream_t stream) {
    const float* x  = (const float*)d_in[0];   // [8192, 2048] fp32
    const float* wg = (const float*)d_in[1];   // [64, 2048] fp32
    float* out = (float*)d_out;

    // ws layout: idx int[8192] @0, gate float[8192] @32768, gsum float[64] @65536
    int*   idx  = (int*)d_ws;
    float* gate = (float*)((char*)d_ws + 32768);
    float* gsum = (float*)((char*)d_ws + 65536);

    // zero the (sparse) giant output, and the gate-sum accumulators
    hipMemsetAsync(d_out, 0, (size_t)out_size * sizeof(float), stream);
    hipMemsetAsync(gsum, 0, NEXP * sizeof(float), stream);

    gate_kernel<<<S_TOK / TOK_PER_BLK, 256, 0, stream>>>(x, wg, idx, gate, gsum);
    scan_scatter<<<1, 1024, 0, stream>>>(idx, gate, gsum, out);
}

// Round 2
// 619.664 us; speedup vs baseline: 1.0239x; 1.0239x over previous
//
#include <hip/hip_runtime.h>
#include <cstdint>
#include <cstddef>

// Top-1 MoE gate. s=8192, e=64, d=2048, cap=128.
// d_out (float32): [l_aux(1), combine(8192*64*128), mask(8192*64*128)]
// Pipeline: logits (split-K fp32 GEMM) -> reduce(+softmax/argmax) -> scan (ranks)
//           -> writer (dense 537MB output, zeros + sparse values fused)

#define S_TOK 8192
#define NEXP 64
#define DIM 2048
#define CAP 128
#define COMB_ELEMS ((size_t)S_TOK * NEXP * CAP)   // 67108864
#define OUT_ELEMS (1 + 2 * COMB_ELEMS)            // 134217729

#define TOK_TILE 128
#define NSLICE 4
#define KSLICE (DIM / NSLICE)   // 512
#define KC 32

// ---------------------------------------------------------------------------
// Kernel 1: split-K logits GEMM. grid = 64 token-tiles x 4 k-slices = 256.
// 256 threads; thread tile 8 tok x 4 exp (LDS 1.5 B/MAC vs 3.0 before).
// Partials P[slice][tok][exp] fp32, reduced deterministically in kernel 2.
// ---------------------------------------------------------------------------
__global__ __launch_bounds__(256) void logits_kernel(
    const float* __restrict__ x, const float* __restrict__ wg,
    float* __restrict__ P)
{
    __shared__ float xs[KC][132];   // k-major x tile, pad 128->132 (bank spread)
    __shared__ float wsh[KC][68];   // k-major wg tile, pad 64->68

    const int tid  = threadIdx.x;
    const int tile  = blockIdx.x >> 2;
    const int slice = blockIdx.x & 3;
    const int tok0 = tile * TOK_TILE;
    const int k0   = slice * KSLICE;

    const int tt = tid >> 4;        // 0..15 -> tokens 8*tt..8*tt+7
    const int te = tid & 15;        // 0..15 -> experts 4*te..4*te+3

    float acc[8][4];
#pragma unroll
    for (int i = 0; i < 8; ++i)
#pragma unroll
        for (int j = 0; j < 4; ++j) acc[i][j] = 0.0f;

    // x staging: 4 float4/thread. idx = tid + 256*r -> t = idx>>3, kq = idx&7
    // wg staging: 2 float4/thread. e = tid&63, kq0 = tid>>6 (and kq0+4)
    const int we  = tid & 63;
    const int wkq = tid >> 6;

    float4 xv[4], wv[2];
#pragma unroll
    for (int r = 0; r < 4; ++r) {
        int idx = tid + 256 * r;
        int t = idx >> 3, kq = idx & 7;
        xv[r] = *(const float4*)(x + (size_t)(tok0 + t) * DIM + k0 + 4 * kq);
    }
    wv[0] = *(const float4*)(wg + (size_t)we * DIM + k0 + 4 * wkq);
    wv[1] = *(const float4*)(wg + (size_t)we * DIM + k0 + 4 * (wkq + 4));

    for (int kc = 0; kc < KSLICE; kc += KC) {
        __syncthreads();
#pragma unroll
        for (int r = 0; r < 4; ++r) {
            int idx = tid + 256 * r;
            int t = idx >> 3, k4 = (idx & 7) * 4;
            xs[k4 + 0][t] = xv[r].x; xs[k4 + 1][t] = xv[r].y;
            xs[k4 + 2][t] = xv[r].z; xs[k4 + 3][t] = xv[r].w;
        }
        {
            int k4 = 4 * wkq;
            wsh[k4 + 0][we] = wv[0].x; wsh[k4 + 1][we] = wv[0].y;
            wsh[k4 + 2][we] = wv[0].z; wsh[k4 + 3][we] = wv[0].w;
            int k4b = k4 + 16;
            wsh[k4b + 0][we] = wv[1].x; wsh[k4b + 1][we] = wv[1].y;
            wsh[k4b + 2][we] = wv[1].z; wsh[k4b + 3][we] = wv[1].w;
        }
        __syncthreads();
        if (kc + KC < KSLICE) {
#pragma unroll
            for (int r = 0; r < 4; ++r) {
                int idx = tid + 256 * r;
                int t = idx >> 3, kq = idx & 7;
                xv[r] = *(const float4*)(x + (size_t)(tok0 + t) * DIM + k0 + kc + KC + 4 * kq);
            }
            wv[0] = *(const float4*)(wg + (size_t)we * DIM + k0 + kc + KC + 4 * wkq);
            wv[1] = *(const float4*)(wg + (size_t)we * DIM + k0 + kc + KC + 4 * (wkq + 4));
        }
#pragma unroll 8
        for (int k = 0; k < KC; ++k) {
            float4 a0 = *(const float4*)&xs[k][8 * tt];
            float4 a1 = *(const float4*)&xs[k][8 * tt + 4];
            float4 b  = *(const float4*)&wsh[k][4 * te];
            const float* ap0 = &a0.x; const float* ap1 = &a1.x; const float* bp = &b.x;
#pragma unroll
            for (int i = 0; i < 4; ++i)
#pragma unroll
                for (int j = 0; j < 4; ++j) {
                    acc[i][j]     += ap0[i] * bp[j];
                    acc[i + 4][j] += ap1[i] * bp[j];
                }
        }
    }

    // store partials: P[(slice*8192 + tok)*64 + e]
#pragma unroll
    for (int i = 0; i < 8; ++i) {
        size_t off = ((size_t)slice * S_TOK + tok0 + 8 * tt + i) * NEXP + 4 * te;
        float4 v = { acc[i][0], acc[i][1], acc[i][2], acc[i][3] };
        *(float4*)(P + off) = v;
    }
}

// ---------------------------------------------------------------------------
// Kernel 2: reduce 4 partials (fixed order) + softmax + argmax + gate sums.
// grid 256 x 256 thr; block = 32 tokens; thread = 4 tok x 2 exp.
// ---------------------------------------------------------------------------
__global__ __launch_bounds__(256) void reduce_kernel(
    const float* __restrict__ P,
    int* __restrict__ idx_out, float* __restrict__ gate_out,
    float* __restrict__ gsum)
{
    __shared__ float sme[NEXP];
    const int tid = threadIdx.x;
    const int tok0 = blockIdx.x * 32;
    const int ty = tid >> 5;          // 0..7
    const int tx = tid & 31;          // 0..31
    const int t0 = ty * 4;
    const int e0 = tx * 2;

    if (tid < NEXP) sme[tid] = 0.0f;

    float gm0 = 0.0f, gm1 = 0.0f;
#pragma unroll
    for (int i = 0; i < 4; ++i) {
        int tok = tok0 + t0 + i;
        float l0 = 0.0f, l1 = 0.0f;
#pragma unroll
        for (int s = 0; s < NSLICE; ++s) {
            float2 p = *(const float2*)&P[((size_t)s * S_TOK + tok) * NEXP + e0];
            l0 += p.x; l1 += p.y;
        }
        float v; int ix;
        if (l1 > l0) { v = l1; ix = e0 + 1; } else { v = l0; ix = e0; }
#pragma unroll
        for (int off = 16; off; off >>= 1) {
            float ov = __shfl_xor(v, off, 32);
            int   oi = __shfl_xor(ix, off, 32);
            if (ov > v || (ov == v && oi < ix)) { v = ov; ix = oi; }
        }
        float z0 = __expf(l0 - v), z1 = __expf(l1 - v);
        float zs = z0 + z1;
#pragma unroll
        for (int off = 16; off; off >>= 1) zs += __shfl_xor(zs, off, 32);
        float inv = 1.0f / zs;
        gm0 += z0 * inv; gm1 += z1 * inv;
        if (tx == 0) {
            idx_out[tok]  = ix;
            gate_out[tok] = inv;
        }
    }
    atomicAdd(&sme[e0], gm0);
    atomicAdd(&sme[e0 + 1], gm1);
    __syncthreads();
    if (tid < NEXP) atomicAdd(&gsum[tid], sme[tid]);
}

// ---------------------------------------------------------------------------
// Kernel 3: ordered per-expert rank via ballots. Writes loc[t] + l_aux (to ws).
// ---------------------------------------------------------------------------
__global__ __launch_bounds__(1024) void scan_kernel(
    const int* __restrict__ idx, const float* __restrict__ gsum,
    int* __restrict__ loc_out, float* __restrict__ laux_out)
{
    __shared__ int wavecnt[16][NEXP];
    __shared__ int basecnt[NEXP];
    const int tid  = threadIdx.x;
    const int lane = tid & 63;
    const int wv   = tid >> 6;

    if (tid < NEXP) basecnt[tid] = 0;
    __syncthreads();

    for (int it = 0; it < S_TOK / 1024; ++it) {
        int tok = it * 1024 + tid;
        int e = idx[tok];
        unsigned long long m = ~0ull, lm = ~0ull;
#pragma unroll
        for (int b = 0; b < 6; ++b) {
            unsigned long long bal = __ballot((e >> b) & 1);
            m  &= ((e >> b) & 1)    ? bal : ~bal;
            lm &= ((lane >> b) & 1) ? bal : ~bal;
        }
        int rank = __popcll(m & ((1ull << lane) - 1ull));
        wavecnt[wv][lane] = __popcll(lm);
        __syncthreads();
        int off = 0;
        for (int w = 0; w < wv; ++w) off += wavecnt[w][e];
        loc_out[tok] = basecnt[e] + off + rank;   // raw rank; >=CAP means dropped
        __syncthreads();
        if (tid < NEXP) {
            int tot = 0;
#pragma unroll
            for (int w = 0; w < 16; ++w) tot += wavecnt[w][tid];
            basecnt[tid] += tot;
        }
        __syncthreads();
    }

    if (tid < NEXP) {
        float p = gsum[tid] * (float)basecnt[tid];
#pragma unroll
        for (int off = 32; off; off >>= 1) p += __shfl_xor(p, off, 64);
        if (tid == 0) laux_out[0] = p * 9.5367431640625e-07f;  // 64/8192^2
    }
}

// ---------------------------------------------------------------------------
// Kernel 4: dense output writer — zeros + sparse values + l_aux in one pass.
// 33,554,432 float4 + 1 tail element. grid 32768 x 256, 4 float4/thread.
// ---------------------------------------------------------------------------
__global__ __launch_bounds__(256) void writer_kernel(
    const int* __restrict__ idx, const float* __restrict__ gate,
    const int* __restrict__ loc, const float* __restrict__ laux,
    float* __restrict__ out)
{
    size_t base = (size_t)blockIdx.x * 1024 + threadIdx.x;
#pragma unroll
    for (int r = 0; r < 4; ++r) {
        size_t j = base + 256 * (size_t)r;
        size_t i0 = j * 4;
        float4 v = { 0.0f, 0.0f, 0.0f, 0.0f };
        float* vp = &v.x;
#pragma unroll
        for (int jj = 0; jj < 4; ++jj) {
            size_t i = i0 + jj;
            if (i == 0) { vp[jj] = laux[0]; continue; }
            size_t q = i - 1;
            bool sel = q >= COMB_ELEMS;               // mask half?
            size_t p = sel ? q - COMB_ELEMS : q;
            int t = (int)(p >> 13);                    // /8192
            int rr = (int)(p & 8191);
            int e = rr >> 7, c = rr & 127;
            if (e == idx[t] && c == loc[t])            // loc>=128 never matches
                vp[jj] = sel ? 1.0f : gate[t];
        }
        *(float4*)(out + i0) = v;
    }
    if (blockIdx.x == 0 && threadIdx.x == 0) {
        // tail element: last mask element (t=8191, e=63, c=127)
        out[OUT_ELEMS - 1] = (idx[S_TOK - 1] == 63 && loc[S_TOK - 1] == 127) ? 1.0f : 0.0f;
    }
}

extern "C" void kernel_launch(void* const* d_in, const int* in_sizes, int n_in,
                              void* d_out, int out_size, void* d_ws, size_t ws_size,
                              hipStream_t stream) {
    const float* x  = (const float*)d_in[0];   // [8192, 2048] fp32
    const float* wg = (const float*)d_in[1];   // [64, 2048] fp32
    float* out = (float*)d_out;

    // ws layout
    int*   idx  = (int*)d_ws;                             // 32 KB
    float* gate = (float*)((char*)d_ws + 32768);          // 32 KB
    float* gsum = (float*)((char*)d_ws + 65536);          // 256 B
    float* laux = (float*)((char*)d_ws + 65792);          // 4 B
    int*   loc  = (int*)((char*)d_ws + 66560);            // 32 KB
    float* P    = (float*)((char*)d_ws + 131072);         // 8 MB partials

    hipMemsetAsync(gsum, 0, NEXP * sizeof(float), stream);

    logits_kernel<<<(S_TOK / TOK_TILE) * NSLICE, 256, 0, stream>>>(x, wg, P);
    reduce_kernel<<<S_TOK / 32, 256, 0, stream>>>(P, idx, gate, gsum);
    scan_kernel<<<1, 1024, 0, stream>>>(idx, gsum, loc, laux);
    writer_kernel<<<32768, 256, 0, stream>>>(idx, gate, loc, laux, out);
}